// Round 18
// baseline (32975.259 us; speedup 1.0000x reference)
//
#include <hip/hip_runtime.h>

// ---------------------------------------------------------------------------
// CNF forward: 2 blocks x Tsit5(10 steps x 6 stages).
// Round 18: ONE ticketed mega-dispatch per stage: jac(i) runs concurrently
//  with the gated chain L0->L1->L2->L3 computing stage i+1. Arrival-order
//  tickets (atomicAdd) make the gate graph deadlock-free regardless of HW
//  dispatch order; handoffs use release-fence + agent-scope gate +
//  acquire-spin + fence (R16-validated). h1/h2 and ky parity-doubled.
//  jac body = R15 (i8 32x32x32, BK=128, counted vmcnt); fwd bodies = R17
//  (2-deep counted-vmcnt pipeline). Boundary stages: chain-only / jac-only.
// ---------------------------------------------------------------------------

using short8 = __attribute__((ext_vector_type(8))) short;
using u16x8  = __attribute__((ext_vector_type(8))) unsigned short;
using f32x4v = __attribute__((ext_vector_type(4))) float;
using i32x4  = __attribute__((ext_vector_type(4))) int;
using u32x4  = __attribute__((ext_vector_type(4))) unsigned;
using i32x16 = __attribute__((ext_vector_type(16))) int;

__device__ __forceinline__ unsigned short f2bf(float f) {
  union { float f; unsigned u; } v; v.f = f;
  unsigned r = v.u + 0x7fffu + ((v.u >> 16) & 1u);
  return (unsigned short)(r >> 16);
}
__device__ __forceinline__ float bf2f(unsigned short h) {
  union { unsigned u; float f; } v; v.u = ((unsigned)h) << 16; return v.f;
}
__device__ __forceinline__ signed char q8(float v, float inv) {
  float r = rintf(v * inv);
  r = fminf(fmaxf(r, -127.f), 127.f);
  return (signed char)(int)r;
}

typedef const __attribute__((address_space(1))) void gas_t;
typedef __attribute__((address_space(3))) void las_t;
__device__ __forceinline__ void gl_lds16(const void* g, void* l) {
  __builtin_amdgcn_global_load_lds((gas_t*)g, (las_t*)l, 16, 0, 0);
}

struct Coef6 { float v[6]; };

#define INV_S0 254.0f
#define INV_S1 508.0f
#define SCALE_J 7.7500155e-06f
#define SCALE_G 3.8750077e-06f

__device__ __forceinline__ void gate_wait(int* g, int target) {
  if (threadIdx.x == 0) {
    while (__hip_atomic_load(g, __ATOMIC_ACQUIRE, __HIP_MEMORY_SCOPE_AGENT) <
           target) {
      __builtin_amdgcn_s_sleep(2);
    }
  }
  __syncthreads();
  __threadfence();
}
__device__ __forceinline__ void gate_bump(int* g) {
  __threadfence();
  __syncthreads();
  if (threadIdx.x == 0)
    __hip_atomic_fetch_add(g, 1, __ATOMIC_RELEASE, __HIP_MEMORY_SCOPE_AGENT);
}

// ---------------------------------------------------------------------------
__global__ __launch_bounds__(256) void init_state(const float* __restrict__ y_in,
                                                  float* __restrict__ y,
                                                  float* __restrict__ lp,
                                                  int* __restrict__ sync) {
  int i = blockIdx.x * 256 + threadIdx.x;
  if (i < 512 * 128) y[i] = y_in[i];
  if (i < 512) lp[i] = 0.f;
  if (i < 1024) sync[i] = 0;
}

// Weight prep (per ODE block): as R13-R17.
__global__ __launch_bounds__(256) void cast_weights(
    const float* __restrict__ W0, const float* __restrict__ W1,
    const float* __restrict__ W2, const float* __restrict__ W3,
    signed char* __restrict__ w0q,
    unsigned short* __restrict__ w0tH, unsigned short* __restrict__ w0tL,
    unsigned short* __restrict__ w1tH, unsigned short* __restrict__ w1tL,
    signed char* __restrict__ w1q,
    unsigned short* __restrict__ w2tH, unsigned short* __restrict__ w2tL,
    unsigned short* __restrict__ w3tH, unsigned short* __restrict__ w3tL,
    signed char* __restrict__ w3q, signed char* __restrict__ w2q) {
  int i = blockIdx.x * 256 + threadIdx.x;
  if (i < 65536) {
    int j = i >> 9, a = i & 511;
    w0q[i] = q8(W0[(1 + j) * 512 + a], INV_S0);
    return;
  }
  i -= 65536;
  if (i >= 2 * 65536 + 2 * 262144) {
    int q = i - (2 * 65536 + 2 * 262144);
    if (q < 262144) w2q[q] = q8(W2[q], INV_S1);
    return;
  }
  float v;
  unsigned short* dh;
  unsigned short* dl;
  signed char* qd = nullptr;
  int di;
  if (i < 65536) {
    int n = i >> 7, k = i & 127;
    v = W0[(1 + k) * 512 + n]; dh = w0tH; dl = w0tL; di = i;
  } else if (i < 65536 + 262144) {
    int q = i - 65536; int n = q >> 9, k = q & 511;
    v = W1[k * 512 + n]; dh = w1tH; dl = w1tL; di = q; qd = w1q;
  } else if (i < 65536 + 2 * 262144) {
    int q = i - 65536 - 262144; int c = q >> 9, b = q & 511;
    v = W2[b * 512 + c]; dh = w2tH; dl = w2tL; di = q;
  } else {
    int q = i - 65536 - 2 * 262144; int j = q >> 9, c = q & 511;
    v = W3[c * 128 + j]; dh = w3tH; dl = w3tL; di = q; qd = w3q;
  }
  unsigned short hi = f2bf(v);
  dh[di] = hi;
  dl[di] = f2bf(v - bf2f(hi));
  if (qd) qd[di] = q8(v, INV_S1);
}

// ---------------------------------------------------------------------------
// fwd body (L1/L2/L3): 32x32 tile, 2-deep counted-vmcnt pipeline (R17).
// ---------------------------------------------------------------------------
__device__ __forceinline__ void fwd_body(
    char* smraw, int m0, int n0, int relu,
    const unsigned short* __restrict__ Ahi, const unsigned short* __restrict__ Alo,
    const unsigned short* __restrict__ WtH, const unsigned short* __restrict__ WtL,
    const float* __restrict__ bias, float* __restrict__ Cf,
    unsigned short* __restrict__ Hhi, unsigned short* __restrict__ Hlo,
    int N, int K) {
  unsigned short* AsH = (unsigned short*)(smraw);
  unsigned short* AsL = (unsigned short*)(smraw + 16384);
  unsigned short* BsH = (unsigned short*)(smraw + 32768);
  unsigned short* BsL = (unsigned short*)(smraw + 49152);
  const int t = threadIdx.x, l = t & 63, w = t >> 6;
  const int wm = w >> 1, wn = w & 1, lr = l & 15, lg = l >> 4;
  const int lr7 = lr & 7;

  auto stage = [&](int cur, int k0) {
#pragma unroll
    for (int r = 0; r < 2; ++r) {
      int g = r * 256 + t;
      int row = g >> 4, gc = g & 15;
      size_t co = (size_t)k0 + ((gc ^ (row & 7)) << 3);
      size_t ao = (size_t)(m0 + row) * K + co;
      size_t bo = (size_t)(n0 + row) * K + co;
      int db = (r * 256 + (t & 192)) * 16 + cur * 8192;
      gl_lds16(Ahi + ao, (char*)AsH + db);
      gl_lds16(Alo + ao, (char*)AsL + db);
      gl_lds16(WtH + bo, (char*)BsH + db);
      gl_lds16(WtL + bo, (char*)BsL + db);
    }
  };

  f32x4v acc = {0.f, 0.f, 0.f, 0.f};
  stage(0, 0);
  stage(1, 128);
  int cur = 0;
  for (int k0 = 0; k0 < K; k0 += 128) {
    if (k0 + 128 < K) {
      asm volatile("s_waitcnt vmcnt(8)" ::: "memory");
    } else {
      asm volatile("s_waitcnt vmcnt(0)" ::: "memory");
    }
    asm volatile("s_barrier" ::: "memory");
#pragma unroll
    for (int ks = 0; ks < 4; ++ks) {
      int sl = ((ks * 4 + lg) ^ lr7) << 4;
      int ab = (wm * 16 + lr) * 256 + sl + cur * 8192;
      int bb = (wn * 16 + lr) * 256 + sl + cur * 8192;
      short8 ah = *(const short8*)((const char*)AsH + ab);
      short8 al = *(const short8*)((const char*)AsL + ab);
      short8 bh = *(const short8*)((const char*)BsH + bb);
      short8 bl = *(const short8*)((const char*)BsL + bb);
      acc = __builtin_amdgcn_mfma_f32_16x16x32_bf16(ah, bh, acc, 0, 0, 0);
      acc = __builtin_amdgcn_mfma_f32_16x16x32_bf16(ah, bl, acc, 0, 0, 0);
      acc = __builtin_amdgcn_mfma_f32_16x16x32_bf16(al, bh, acc, 0, 0, 0);
    }
    asm volatile("s_waitcnt lgkmcnt(0)" ::: "memory");
    asm volatile("s_barrier" ::: "memory");
    if (k0 + 256 < K) stage(cur, k0 + 256);
    cur ^= 1;
  }

  int n = n0 + wn * 16 + lr;
  float be = bias[n];
#pragma unroll
  for (int r = 0; r < 4; ++r) {
    int m = m0 + wm * 16 + lg * 4 + r;
    float v = acc[r] + be;
    if (relu) {
      v = fmaxf(v, 0.f);
      unsigned short h = f2bf(v);
      Hhi[m * N + n] = h;
      Hlo[m * N + n] = f2bf(v - bf2f(h));
    } else {
      Cf[m * N + n] = v;
    }
  }
}

// ---------------------------------------------------------------------------
// Mega dispatch: tickets (arrival order) map to roles.
//  chain=1,njac=1024: [L0 256][jac 256][L1 256][jac 256][L2 256][jac 256]
//                     [L3 64][jac 256]  (grid 1856)
//  chain=1,njac=0:    [L0][L1][L2][L3]  (grid 832)   -- bootstrap
//  chain=0:           all jac           (grid 1024)  -- last stage of block
// Gates: sync[1]=gL0(256), sync[2]=gL1(256), sync[3]=gL2(256).
// ---------------------------------------------------------------------------
__global__ __launch_bounds__(256, 2) void mega(
    int* __restrict__ sync, int chain, int njac,
    const signed char* __restrict__ w1q, const signed char* __restrict__ w0q,
    const signed char* __restrict__ w2q, const signed char* __restrict__ w3q,
    const unsigned short* __restrict__ d0m, const unsigned short* __restrict__ d1m,
    const unsigned short* __restrict__ d2m, float* __restrict__ klp,
    const float* __restrict__ yb, const float* __restrict__ kyRead, Coef6 ca,
    int nc, const unsigned short* __restrict__ w0tH,
    const unsigned short* __restrict__ w0tL, const float* __restrict__ b0,
    const float* __restrict__ wrow0, float tval,
    unsigned short* __restrict__ h0oH, unsigned short* __restrict__ h0oL,
    const unsigned short* __restrict__ w1tH, const unsigned short* __restrict__ w1tL,
    const float* __restrict__ b1,
    unsigned short* __restrict__ h1oH, unsigned short* __restrict__ h1oL,
    const unsigned short* __restrict__ w2tH, const unsigned short* __restrict__ w2tL,
    const float* __restrict__ b2,
    unsigned short* __restrict__ h2oH, unsigned short* __restrict__ h2oL,
    const unsigned short* __restrict__ w3tH, const unsigned short* __restrict__ w3tL,
    const float* __restrict__ b3, float* __restrict__ kyWrite) {
  __shared__ __align__(16) char smraw[68672];
  __shared__ int tkS;
  const int t = threadIdx.x, l = t & 63, w = t >> 6;

  if (t == 0) tkS = atomicAdd(&sync[0], 1);
  __syncthreads();
  const int tk = tkS;

  int role, idx;
  if (!chain) {
    role = 0; idx = tk;
  } else if (njac == 0) {
    if (tk < 256) { role = 1; idx = tk; }
    else if (tk < 512) { role = 2; idx = tk - 256; }
    else if (tk < 768) { role = 3; idx = tk - 512; }
    else { role = 4; idx = tk - 768; }
  } else {
    if (tk < 256) { role = 1; idx = tk; }
    else if (tk < 512) { role = 0; idx = tk - 256; }
    else if (tk < 768) { role = 2; idx = tk - 512; }
    else if (tk < 1024) { role = 0; idx = tk - 768 + 256; }
    else if (tk < 1280) { role = 3; idx = tk - 1024; }
    else if (tk < 1536) { role = 0; idx = tk - 1280 + 512; }
    else if (tk < 1600) { role = 4; idx = tk - 1536; }
    else { role = 0; idx = tk - 1600 + 768; }
  }

  if (role == 1) {
    // ------------------------------- L0 -----------------------------------
    unsigned short* AsH = (unsigned short*)(smraw);
    unsigned short* AsL = (unsigned short*)(smraw + 8192);
    unsigned short* BsH = (unsigned short*)(smraw + 16384);
    unsigned short* BsL = (unsigned short*)(smraw + 24576);
    const int wm = w >> 1, wn = w & 1, lr = l & 15, lg = l >> 4, lr7 = lr & 7;
    const int m0 = (idx >> 4) * 32, n0 = (idx & 15) * 32;

#pragma unroll
    for (int r = 0; r < 2; ++r) {
      int g = r * 256 + t;
      int row = g >> 4;
      int gc = (g & 15) ^ (row & 7);
      size_t bo = (size_t)(n0 + row) * 128 + gc * 8;
      int db = (r * 256 + (t & 192)) * 16;
      gl_lds16(w0tH + bo, (char*)BsH + db);
      gl_lds16(w0tL + bo, (char*)BsL + db);
    }
    {
      int row = t >> 3, seg = t & 7;
      int gidx = (m0 + row) * 128 + seg * 16;
      float x[16];
#pragma unroll
      for (int q = 0; q < 4; ++q)
        *(float4*)&x[q * 4] = *(const float4*)&yb[gidx + q * 4];
      for (int j2 = 0; j2 < nc; ++j2) {
        float c = ca.v[j2];
#pragma unroll
        for (int q = 0; q < 4; ++q) {
          float4 u = *(const float4*)&kyRead[j2 * 65536 + gidx + q * 4];
          x[q * 4 + 0] = fmaf(c, u.x, x[q * 4 + 0]);
          x[q * 4 + 1] = fmaf(c, u.y, x[q * 4 + 1]);
          x[q * 4 + 2] = fmaf(c, u.z, x[q * 4 + 2]);
          x[q * 4 + 3] = fmaf(c, u.w, x[q * 4 + 3]);
        }
      }
      u16x8 h8[2], l8[2];
#pragma unroll
      for (int e = 0; e < 16; ++e) {
        unsigned short hh = f2bf(x[e]);
        h8[e >> 3][e & 7] = hh;
        l8[e >> 3][e & 7] = f2bf(x[e] - bf2f(hh));
      }
#pragma unroll
      for (int h = 0; h < 2; ++h) {
        int gx = (seg * 2 + h) ^ (row & 7);
        *(u16x8*)((char*)AsH + row * 256 + gx * 16) = h8[h];
        *(u16x8*)((char*)AsL + row * 256 + gx * 16) = l8[h];
      }
    }
    __syncthreads();

    f32x4v acc = {0.f, 0.f, 0.f, 0.f};
#pragma unroll
    for (int ks = 0; ks < 4; ++ks) {
      int sl = ((ks * 4 + lg) ^ lr7) << 4;
      int ab = (wm * 16 + lr) * 256 + sl;
      int bb = (wn * 16 + lr) * 256 + sl;
      short8 ah = *(const short8*)((const char*)AsH + ab);
      short8 al = *(const short8*)((const char*)AsL + ab);
      short8 bh = *(const short8*)((const char*)BsH + bb);
      short8 bl = *(const short8*)((const char*)BsL + bb);
      acc = __builtin_amdgcn_mfma_f32_16x16x32_bf16(ah, bh, acc, 0, 0, 0);
      acc = __builtin_amdgcn_mfma_f32_16x16x32_bf16(ah, bl, acc, 0, 0, 0);
      acc = __builtin_amdgcn_mfma_f32_16x16x32_bf16(al, bh, acc, 0, 0, 0);
    }

    int n = n0 + wn * 16 + lr;
    float be = fmaf(tval, wrow0[n], b0[n]);
#pragma unroll
    for (int r = 0; r < 4; ++r) {
      int m = m0 + wm * 16 + lg * 4 + r;
      float v = fmaxf(acc[r] + be, 0.f);
      unsigned short h = f2bf(v);
      h0oH[m * 512 + n] = h;
      h0oL[m * 512 + n] = f2bf(v - bf2f(h));
    }
    gate_bump(&sync[1]);
    return;
  }
  if (role == 2) {
    gate_wait(&sync[1], 256);
    fwd_body(smraw, (idx >> 4) * 32, (idx & 15) * 32, 1, h0oH, h0oL, w1tH, w1tL,
             b1, nullptr, h1oH, h1oL, 512, 512);
    gate_bump(&sync[2]);
    return;
  }
  if (role == 3) {
    gate_wait(&sync[2], 256);
    fwd_body(smraw, (idx >> 4) * 32, (idx & 15) * 32, 1, h1oH, h1oL, w2tH, w2tL,
             b2, nullptr, h2oH, h2oL, 512, 512);
    gate_bump(&sync[3]);
    return;
  }
  if (role == 4) {
    gate_wait(&sync[3], 256);
    fwd_body(smraw, (idx >> 2) * 32, (idx & 3) * 32, 0, h2oH, h2oL, w3tH, w3tL,
             b3, kyWrite, nullptr, nullptr, 128, 512);
    return;
  }

  // -------------------------------- jac -----------------------------------
  signed char* As = (signed char*)smraw;
  signed char* Bs = (signed char*)(smraw + 32768);
  unsigned char* Ms8 = (unsigned char*)(smraw + 65536);
  float* red = (float*)(smraw + 68608);
  const int cb = idx & 3, s0 = (idx >> 2) * 2;
  const int wm = w >> 1, wn = w & 1;
  const int lr31 = l & 31, hi = l >> 5;

  if (w < 3) {
    const unsigned short* src = (w == 0) ? d0m : (w == 1) ? d1m : d2m;
    gl_lds16(src + (size_t)s0 * 512 + l * 8, As + w * 2048);
    gl_lds16(src + (size_t)(s0 + 1) * 512 + l * 8, As + w * 2048 + 1024);
  }
  __syncthreads();
  {
    const unsigned* Mraw = (const unsigned*)As;
    unsigned* Mout = (unsigned*)Ms8;
#pragma unroll
    for (int q = 0; q < 3; ++q) {
      int i = q * 256 + t;
      unsigned lo = Mraw[2 * i], hi2 = Mraw[2 * i + 1];
      unsigned m = 0;
      if (lo & 0xFFFFu) m |= 0x000000FFu;
      if (lo >> 16)     m |= 0x0000FF00u;
      if (hi2 & 0xFFFFu) m |= 0x00FF0000u;
      if (hi2 >> 16)     m |= 0xFF000000u;
      Mout[i] = m;
    }
  }
  __syncthreads();

  auto stage = [&](int buf, const signed char* Aq, const signed char* Bq, int k0) {
#pragma unroll
    for (int i = 0; i < 8; ++i) {
      int u = i * 4 + w;
      int uu = (u < 16) ? u : (u - 16);
      int g = uu * 64 + l;
      int row = g & 127;
      int kh = (g >> 7) & 1;
      int ks = g >> 8;
      int kb = k0 + ks * 32 + kh * 16;
      if (u < 16)
        gl_lds16(Aq + (size_t)(cb * 128 + row) * 512 + kb, As + buf * 16384 + uu * 1024);
      else
        gl_lds16(Bq + (size_t)row * 512 + kb, Bs + buf * 16384 + uu * 1024);
    }
  };

  i32x16 a0[2][2], a1[2][2];
  auto phase = [&](const signed char* Aq, const signed char* Bq, int mbase) {
#pragma unroll
    for (int mt = 0; mt < 2; ++mt)
#pragma unroll
      for (int nt = 0; nt < 2; ++nt) {
        a0[mt][nt] = (i32x16)(0);
        a1[mt][nt] = (i32x16)(0);
      }
    stage(0, Aq, Bq, 0);
    int cur = 0;
    for (int k0 = 0; k0 < 512; k0 += 128) {
      if (k0 + 128 < 512) {
        stage(cur ^ 1, Aq, Bq, k0 + 128);
        asm volatile("s_waitcnt vmcnt(8)" ::: "memory");
      } else {
        asm volatile("s_waitcnt vmcnt(0)" ::: "memory");
      }
      asm volatile("s_barrier" ::: "memory");
      __builtin_amdgcn_s_setprio(1);
#pragma unroll
      for (int ks = 0; ks < 4; ++ks) {
        i32x4 af[2];
#pragma unroll
        for (int mt = 0; mt < 2; ++mt)
          af[mt] = *(const i32x4*)(As + cur * 16384 +
                                   (ks * 256 + hi * 128 + wm * 64 + mt * 32 + lr31) * 16);
        u32x4 mk0 = *(const u32x4*)&Ms8[mbase + k0 + ks * 32 + hi * 16];
        u32x4 mk1 = *(const u32x4*)&Ms8[mbase + 512 + k0 + ks * 32 + hi * 16];
#pragma unroll
        for (int nt = 0; nt < 2; ++nt) {
          u32x4 bv = *(const u32x4*)(Bs + cur * 16384 +
                                     (ks * 256 + hi * 128 + wn * 64 + nt * 32 + lr31) * 16);
          i32x4 b0v = (i32x4)(bv & mk0);
          i32x4 b1v = (i32x4)(bv & mk1);
#pragma unroll
          for (int mt = 0; mt < 2; ++mt) {
            a0[mt][nt] = __builtin_amdgcn_mfma_i32_32x32x32_i8(af[mt], b0v,
                                                               a0[mt][nt], 0, 0, 0);
            a1[mt][nt] = __builtin_amdgcn_mfma_i32_32x32x32_i8(af[mt], b1v,
                                                               a1[mt][nt], 0, 0, 0);
          }
        }
      }
      __builtin_amdgcn_s_setprio(0);
      asm volatile("s_waitcnt lgkmcnt(0)" ::: "memory");
      asm volatile("s_barrier" ::: "memory");
      cur ^= 1;
    }
  };

  phase(w2q, w3q, 2 * 1024);
  unsigned pg0[2][2][8], pg1[2][2][8];
#pragma unroll
  for (int mt = 0; mt < 2; ++mt)
#pragma unroll
    for (int nt = 0; nt < 2; ++nt)
#pragma unroll
      for (int p = 0; p < 8; ++p) {
        float ga = (float)a0[mt][nt][2 * p] * SCALE_G;
        float gb = (float)a0[mt][nt][2 * p + 1] * SCALE_G;
        float gc = (float)a1[mt][nt][2 * p] * SCALE_G;
        float gd = (float)a1[mt][nt][2 * p + 1] * SCALE_G;
        asm("v_cvt_pk_bf16_f32 %0, %1, %2" : "=v"(pg0[mt][nt][p]) : "v"(ga), "v"(gb));
        asm("v_cvt_pk_bf16_f32 %0, %1, %2" : "=v"(pg1[mt][nt][p]) : "v"(gc), "v"(gd));
      }

  phase(w1q, w0q, 0);

  float p0 = 0.f, p1 = 0.f;
  const unsigned char* D1b = &Ms8[1 * 1024];
#pragma unroll
  for (int mt = 0; mt < 2; ++mt) {
#pragma unroll
    for (int q = 0; q < 4; ++q) {
      int blg = cb * 128 + wm * 64 + mt * 32 + q * 8 + 4 * hi;
      uchar4 m40 = *(const uchar4*)&D1b[blg];
      uchar4 m41 = *(const uchar4*)&D1b[512 + blg];
      unsigned char mm0[4] = {m40.x, m40.y, m40.z, m40.w};
      unsigned char mm1[4] = {m41.x, m41.y, m41.z, m41.w};
#pragma unroll
      for (int e = 0; e < 4; ++e) {
        const int r = q * 4 + e;
#pragma unroll
        for (int nt = 0; nt < 2; ++nt) {
          unsigned pw0 = pg0[mt][nt][r >> 1];
          unsigned pw1 = pg1[mt][nt][r >> 1];
          unsigned short g0 = (r & 1) ? (unsigned short)(pw0 >> 16)
                                      : (unsigned short)(pw0 & 0xFFFFu);
          unsigned short g1 = (r & 1) ? (unsigned short)(pw1 >> 16)
                                      : (unsigned short)(pw1 & 0xFFFFu);
          if (mm0[e]) p0 = fmaf((float)a0[mt][nt][r], bf2f(g0), p0);
          if (mm1[e]) p1 = fmaf((float)a1[mt][nt][r], bf2f(g1), p1);
        }
      }
    }
  }
  p0 *= SCALE_J;
  p1 *= SCALE_J;
#pragma unroll
  for (int off = 1; off < 64; off <<= 1) {
    p0 += __shfl_xor(p0, off);
    p1 += __shfl_xor(p1, off);
  }
  if (l == 0) { red[w * 2] = p0; red[w * 2 + 1] = p1; }
  __syncthreads();
  if (t < 2) {
    klp[cb * 512 + s0 + t] = red[t] + red[2 + t] + red[4 + t] + red[6 + t];
  }
}

// y += sum_i db[i]*ky[i];  lp += sum_i db[i]*(sum_{4 chunks} klp[i][cb][s])
__global__ __launch_bounds__(256) void step_update(float* __restrict__ y,
                                                   float* __restrict__ lp,
                                                   const float* __restrict__ ky,
                                                   const float* __restrict__ klp_part,
                                                   Coef6 db) {
  int i = blockIdx.x * 256 + threadIdx.x;
  if (i < 65536) {
    float a = y[i];
#pragma unroll
    for (int j = 0; j < 6; ++j) a += db.v[j] * ky[j * 65536 + i];
    y[i] = a;
  }
  if (i < 512) {
    float l = lp[i];
#pragma unroll
    for (int j = 0; j < 6; ++j) {
      const float* kp = klp_part + j * 2048;
      float tr = kp[i] + kp[512 + i] + kp[1024 + i] + kp[1536 + i];
      l += db.v[j] * tr;
    }
    lp[i] = l;
  }
}

__global__ __launch_bounds__(64) void finalize(const float* __restrict__ y,
                                               const float* __restrict__ lp,
                                               float* __restrict__ out) {
  int s = blockIdx.x, l = threadIdx.x;
  float v0 = y[s * 128 + l], v1 = y[s * 128 + 64 + l];
  float sum = v0 * v0 + v1 * v1;
#pragma unroll
  for (int off = 32; off; off >>= 1) sum += __shfl_down(sum, off);
  if (l == 0) out[s] = lp[s] + (-0.5f) * (1.8378770664093453f + sum);
}

// ---------------------------------------------------------------------------
extern "C" void kernel_launch(void* const* d_in, const int* in_sizes, int n_in,
                              void* d_out, int out_size, void* d_ws, size_t ws_size,
                              hipStream_t stream) {
  const float* y_in = (const float*)d_in[0];
  const float* Ws0 = (const float*)d_in[1];
  const float* bs0 = (const float*)d_in[2];
  const float* Ws1 = (const float*)d_in[3];
  const float* bs1 = (const float*)d_in[4];
  const float* Ws2 = (const float*)d_in[5];
  const float* bs2 = (const float*)d_in[6];
  const float* Ws3 = (const float*)d_in[7];
  const float* bs3 = (const float*)d_in[8];
  float* out = (float*)d_out;

  char* ws = (char*)d_ws;
  size_t off = 0;
  auto alloc = [&](size_t bytes) {
    void* p = ws + off;
    off = (off + bytes + 255) & ~(size_t)255;
    return p;
  };
  float* y  = (float*)alloc(65536 * 4);
  float* lp = (float*)alloc(512 * 4);
  int* sync = (int*)alloc(1024 * 4);
  unsigned short* h0hi[2] = {(unsigned short*)alloc(262144 * 2),
                             (unsigned short*)alloc(262144 * 2)};
  unsigned short* h0lo[2] = {(unsigned short*)alloc(262144 * 2),
                             (unsigned short*)alloc(262144 * 2)};
  unsigned short* h1hi[2] = {(unsigned short*)alloc(262144 * 2),
                             (unsigned short*)alloc(262144 * 2)};
  unsigned short* h1lo[2] = {(unsigned short*)alloc(262144 * 2),
                             (unsigned short*)alloc(262144 * 2)};
  unsigned short* h2hi[2] = {(unsigned short*)alloc(262144 * 2),
                             (unsigned short*)alloc(262144 * 2)};
  unsigned short* h2lo[2] = {(unsigned short*)alloc(262144 * 2),
                             (unsigned short*)alloc(262144 * 2)};
  float* ky[2] = {(float*)alloc(6 * 65536 * 4), (float*)alloc(6 * 65536 * 4)};
  float* klp = (float*)alloc(6 * 2048 * 4);
  unsigned short* w0tH = (unsigned short*)alloc(65536 * 2);
  unsigned short* w0tL = (unsigned short*)alloc(65536 * 2);
  unsigned short* w1tH = (unsigned short*)alloc(262144 * 2);
  unsigned short* w1tL = (unsigned short*)alloc(262144 * 2);
  unsigned short* w2tH = (unsigned short*)alloc(262144 * 2);
  unsigned short* w2tL = (unsigned short*)alloc(262144 * 2);
  unsigned short* w3tH = (unsigned short*)alloc(65536 * 2);
  unsigned short* w3tL = (unsigned short*)alloc(65536 * 2);
  signed char* w0q = (signed char*)alloc(65536);
  signed char* w1q = (signed char*)alloc(262144);
  signed char* w2q = (signed char*)alloc(262144);
  signed char* w3q = (signed char*)alloc(65536);
  (void)ws_size; (void)in_sizes; (void)n_in; (void)out_size;

  static const double DT = -0.1;
  static const double TC[6] = {0.0, 0.161, 0.327, 0.9, 0.9800255409045097, 1.0};
  static const double TA[6][5] = {
      {0, 0, 0, 0, 0},
      {0.161, 0, 0, 0, 0},
      {-0.008480655492356989, 0.335480655492357, 0, 0, 0},
      {2.8971530571054935, -6.359448489975075, 4.3622954328695815, 0, 0},
      {5.325864828439257, -11.748883564062828, 7.4955393428898365, -0.09249506636175525, 0},
      {5.86145544294642, -12.92096931784711, 8.159367898576159, -0.071584973281401,
       -0.028269050394068383}};
  static const double TB[6] = {0.09646076681806523, 0.01, 0.4798896504144996,
                               1.379008574103742, -3.290069515436081, 2.324710524099774};

  Coef6 db;
  for (int i2 = 0; i2 < 6; ++i2) db.v[i2] = (float)(DT * TB[i2]);
  Coef6 c0 = {{0, 0, 0, 0, 0, 0}};

  init_state<<<dim3(256), dim3(256), 0, stream>>>(y_in, y, lp, sync);

  int dc = 0;  // dispatch counter -> sync slot base
  for (int blk = 0; blk < 2; ++blk) {
    const float* W0 = Ws0 + blk * 129 * 512;
    const float* b0 = bs0 + blk * 512;
    const float* W1 = Ws1 + blk * 262144;
    const float* b1 = bs1 + blk * 512;
    const float* W2 = Ws2 + blk * 262144;
    const float* b2 = bs2 + blk * 512;
    const float* W3 = Ws3 + blk * 65536;
    const float* b3 = bs3 + blk * 128;

    cast_weights<<<dim3(3840), dim3(256), 0, stream>>>(
        W0, W1, W2, W3, w0q, w0tH, w0tL, w1tH, w1tL, w1q,
        w2tH, w2tL, w3tH, w3tL, w3q, w2q);

    // Bootstrap: chain-only computes stage 0's h (parity 0) and ky[0][0].
    mega<<<dim3(832), 256, 0, stream>>>(
        sync + 4 * (dc++), 1, 0, w1q, w0q, w2q, w3q,
        h0hi[0], h1hi[0], h2hi[0], klp,
        y, ky[0], c0, 0, w0tH, w0tL, b0, W0, 1.0f, h0hi[0], h0lo[0],
        w1tH, w1tL, b1, h1hi[0], h1lo[0],
        w2tH, w2tL, b2, h2hi[0], h2lo[0],
        w3tH, w3tL, b3, ky[0]);

    for (int n = 0; n < 10; ++n) {
      float tn = 1.0f + (-0.1f) * (float)n;
      const int sp = n & 1;
      for (int i = 0; i < 6; ++i) {
        const int p = i & 1;
        if (n == 9 && i == 5) {
          // jac only (end of ODE block).
          mega<<<dim3(1024), 256, 0, stream>>>(
              sync + 4 * (dc++), 0, 1024, w1q, w0q, w2q, w3q,
              h0hi[p], h1hi[p], h2hi[p], klp + 5 * 2048,
              y, ky[sp], c0, 0, w0tH, w0tL, b0, W0, tn, h0hi[p ^ 1], h0lo[p ^ 1],
              w1tH, w1tL, b1, h1hi[p ^ 1], h1lo[p ^ 1],
              w2tH, w2tL, b2, h2hi[p ^ 1], h2lo[p ^ 1],
              w3tH, w3tL, b3, ky[sp ^ 1]);
        } else if (i == 5) {
          // jac(5) + chain for stage (n+1, 0): ca=db, writes h parity 0,
          // ky[sp^1][0].
          float tin = tn - 0.1f;
          mega<<<dim3(1856), 256, 0, stream>>>(
              sync + 4 * (dc++), 1, 1024, w1q, w0q, w2q, w3q,
              h0hi[p], h1hi[p], h2hi[p], klp + 5 * 2048,
              y, ky[sp], db, 6, w0tH, w0tL, b0, W0, tin, h0hi[p ^ 1], h0lo[p ^ 1],
              w1tH, w1tL, b1, h1hi[p ^ 1], h1lo[p ^ 1],
              w2tH, w2tL, b2, h2hi[p ^ 1], h2lo[p ^ 1],
              w3tH, w3tL, b3, ky[sp ^ 1]);
        } else {
          // jac(i) + chain for stage (i+1).
          Coef6 cn = {{0, 0, 0, 0, 0, 0}};
          for (int j = 0; j <= i; ++j) cn.v[j] = (float)(DT * TA[i + 1][j]);
          float tin = tn + (float)(TC[i + 1] * DT);
          mega<<<dim3(1856), 256, 0, stream>>>(
              sync + 4 * (dc++), 1, 1024, w1q, w0q, w2q, w3q,
              h0hi[p], h1hi[p], h2hi[p], klp + i * 2048,
              y, ky[sp], cn, i + 1, w0tH, w0tL, b0, W0, tin,
              h0hi[p ^ 1], h0lo[p ^ 1],
              w1tH, w1tL, b1, h1hi[p ^ 1], h1lo[p ^ 1],
              w2tH, w2tL, b2, h2hi[p ^ 1], h2lo[p ^ 1],
              w3tH, w3tL, b3, ky[sp] + (i + 1) * 65536);
        }
      }
      step_update<<<dim3(256), dim3(256), 0, stream>>>(y, lp, ky[sp], klp, db);
    }
  }
  finalize<<<dim3(512), dim3(64), 0, stream>>>(y, lp, out);
}

// Round 19
// 7232.569 us; speedup vs baseline: 4.5593x; 4.5593x over previous
//
#include <hip/hip_runtime.h>

// ---------------------------------------------------------------------------
// CNF forward: 2 blocks x Tsit5(10 steps x 6 stages).
// Round 19 = Round 17 reverted verbatim (best: 7.236 ms).
//  R18's ticketed intra-dispatch gating livelocked the scheduler (rocprof:
//  occupancy 10%, MfmaUtil 2%, mega dispatches 20-80 ms) -- spinning consumer
//  blocks hold resident slots while producer blocks wait in the queue.
//  Frame: i8 32x32x32 jac (BK=128, counted vmcnt, setprio) + L0-of-next-stage
//  merged into the jac dispatch (independent work only, no gating) + fwd
//  L1/L2/L3 as separate dispatches with 2-deep counted-vmcnt pipeline.
// ---------------------------------------------------------------------------

using short8 = __attribute__((ext_vector_type(8))) short;
using u16x8  = __attribute__((ext_vector_type(8))) unsigned short;
using f32x4v = __attribute__((ext_vector_type(4))) float;
using i32x4  = __attribute__((ext_vector_type(4))) int;
using u32x4  = __attribute__((ext_vector_type(4))) unsigned;
using i32x16 = __attribute__((ext_vector_type(16))) int;

__device__ __forceinline__ unsigned short f2bf(float f) {
  union { float f; unsigned u; } v; v.f = f;
  unsigned r = v.u + 0x7fffu + ((v.u >> 16) & 1u);
  return (unsigned short)(r >> 16);
}
__device__ __forceinline__ float bf2f(unsigned short h) {
  union { unsigned u; float f; } v; v.u = ((unsigned)h) << 16; return v.f;
}
__device__ __forceinline__ signed char q8(float v, float inv) {
  float r = rintf(v * inv);
  r = fminf(fmaxf(r, -127.f), 127.f);
  return (signed char)(int)r;
}

typedef const __attribute__((address_space(1))) void gas_t;
typedef __attribute__((address_space(3))) void las_t;
__device__ __forceinline__ void gl_lds16(const void* g, void* l) {
  __builtin_amdgcn_global_load_lds((gas_t*)g, (las_t*)l, 16, 0, 0);
}

struct Coef6 { float v[6]; };

#define INV_S0 254.0f
#define INV_S1 508.0f
#define SCALE_J 7.7500155e-06f
#define SCALE_G 3.8750077e-06f

// ---------------------------------------------------------------------------
__global__ __launch_bounds__(256) void init_state(const float* __restrict__ y_in,
                                                  float* __restrict__ y,
                                                  float* __restrict__ lp) {
  int i = blockIdx.x * 256 + threadIdx.x;
  if (i < 512 * 128) y[i] = y_in[i];
  if (i < 512) lp[i] = 0.f;
}

// Weight prep (per ODE block): as R13-R15.
__global__ __launch_bounds__(256) void cast_weights(
    const float* __restrict__ W0, const float* __restrict__ W1,
    const float* __restrict__ W2, const float* __restrict__ W3,
    signed char* __restrict__ w0q,
    unsigned short* __restrict__ w0tH, unsigned short* __restrict__ w0tL,
    unsigned short* __restrict__ w1tH, unsigned short* __restrict__ w1tL,
    signed char* __restrict__ w1q,
    unsigned short* __restrict__ w2tH, unsigned short* __restrict__ w2tL,
    unsigned short* __restrict__ w3tH, unsigned short* __restrict__ w3tL,
    signed char* __restrict__ w3q, signed char* __restrict__ w2q) {
  int i = blockIdx.x * 256 + threadIdx.x;
  if (i < 65536) {
    int j = i >> 9, a = i & 511;
    w0q[i] = q8(W0[(1 + j) * 512 + a], INV_S0);
    return;
  }
  i -= 65536;
  if (i >= 2 * 65536 + 2 * 262144) {
    int q = i - (2 * 65536 + 2 * 262144);
    if (q < 262144) w2q[q] = q8(W2[q], INV_S1);
    return;
  }
  float v;
  unsigned short* dh;
  unsigned short* dl;
  signed char* qd = nullptr;
  int di;
  if (i < 65536) {
    int n = i >> 7, k = i & 127;
    v = W0[(1 + k) * 512 + n]; dh = w0tH; dl = w0tL; di = i;
  } else if (i < 65536 + 262144) {
    int q = i - 65536; int n = q >> 9, k = q & 511;
    v = W1[k * 512 + n]; dh = w1tH; dl = w1tL; di = q; qd = w1q;
  } else if (i < 65536 + 2 * 262144) {
    int q = i - 65536 - 262144; int c = q >> 9, b = q & 511;
    v = W2[b * 512 + c]; dh = w2tH; dl = w2tL; di = q;
  } else {
    int q = i - 65536 - 2 * 262144; int j = q >> 9, c = q & 511;
    v = W3[c * 128 + j]; dh = w3tH; dl = w3tL; di = q; qd = w3q;
  }
  unsigned short hi = f2bf(v);
  dh[di] = hi;
  dl[di] = f2bf(v - bf2f(hi));
  if (qd) qd[di] = q8(v, INV_S1);
}

// ---------------------------------------------------------------------------
// fwd split-bf16 MFMA GEMM (L1/L2/L3): 32x32 tile, K=512 as 4 tiles of 128,
// 2-deep counted-vmcnt pipeline (tiles 0,1 prologue-staged; steady state
// keeps 16 loads in flight, waits only the older 8).
// ---------------------------------------------------------------------------
template <bool RELU>
__global__ __launch_bounds__(256, 2) void fwd_mfma(
    const unsigned short* __restrict__ Ahi, const unsigned short* __restrict__ Alo,
    const unsigned short* __restrict__ WtH, const unsigned short* __restrict__ WtL,
    const float* __restrict__ bias,
    float* __restrict__ Cf, unsigned short* __restrict__ Hhi,
    unsigned short* __restrict__ Hlo, int N, int K) {
  __shared__ unsigned short AsH[2][4096], AsL[2][4096], BsH[2][4096], BsL[2][4096];
  const int t = threadIdx.x, l = t & 63, w = t >> 6;
  const int wm = w >> 1, wn = w & 1, lr = l & 15, lg = l >> 4;
  const int m0 = blockIdx.y * 32, n0 = blockIdx.x * 32;
  const int lr7 = lr & 7;

  auto stage = [&](int cur, int k0) {
#pragma unroll
    for (int r = 0; r < 2; ++r) {
      int g = r * 256 + t;
      int row = g >> 4, gc = g & 15;
      size_t co = (size_t)k0 + ((gc ^ (row & 7)) << 3);
      size_t ao = (size_t)(m0 + row) * K + co;
      size_t bo = (size_t)(n0 + row) * K + co;
      int db = (r * 256 + (t & 192)) * 16;
      gl_lds16(Ahi + ao, (char*)AsH[cur] + db);
      gl_lds16(Alo + ao, (char*)AsL[cur] + db);
      gl_lds16(WtH + bo, (char*)BsH[cur] + db);
      gl_lds16(WtL + bo, (char*)BsL[cur] + db);
    }
  };

  f32x4v acc = {0.f, 0.f, 0.f, 0.f};
  stage(0, 0);
  if (K > 128) stage(1, 128);
  int cur = 0;
  for (int k0 = 0; k0 < K; k0 += 128) {
    if (k0 + 128 < K) {
      asm volatile("s_waitcnt vmcnt(8)" ::: "memory");
    } else {
      asm volatile("s_waitcnt vmcnt(0)" ::: "memory");
    }
    asm volatile("s_barrier" ::: "memory");
#pragma unroll
    for (int ks = 0; ks < 4; ++ks) {
      int sl = ((ks * 4 + lg) ^ lr7) << 4;
      int ab = (wm * 16 + lr) * 256 + sl;
      int bb = (wn * 16 + lr) * 256 + sl;
      short8 ah = *(const short8*)((const char*)AsH[cur] + ab);
      short8 al = *(const short8*)((const char*)AsL[cur] + ab);
      short8 bh = *(const short8*)((const char*)BsH[cur] + bb);
      short8 bl = *(const short8*)((const char*)BsL[cur] + bb);
      acc = __builtin_amdgcn_mfma_f32_16x16x32_bf16(ah, bh, acc, 0, 0, 0);
      acc = __builtin_amdgcn_mfma_f32_16x16x32_bf16(ah, bl, acc, 0, 0, 0);
      acc = __builtin_amdgcn_mfma_f32_16x16x32_bf16(al, bh, acc, 0, 0, 0);
    }
    asm volatile("s_waitcnt lgkmcnt(0)" ::: "memory");
    asm volatile("s_barrier" ::: "memory");
    if (k0 + 256 < K) stage(cur, k0 + 256);
    cur ^= 1;
  }

  int n = n0 + wn * 16 + lr;
  float be = bias[n];
#pragma unroll
  for (int r = 0; r < 4; ++r) {
    int m = m0 + wm * 16 + lg * 4 + r;
    float v = acc[r] + be;
    if (RELU) {
      v = fmaxf(v, 0.f);
      unsigned short h = f2bf(v);
      Hhi[m * N + n] = h;
      Hlo[m * N + n] = f2bf(v - bf2f(h));
    } else {
      Cf[m * N + n] = v;
    }
  }
}

// ---------------------------------------------------------------------------
// Merged kernel (R15): blocks [0, l0n) = fwd L0 of the NEXT stage; blocks
// [l0n, l0n+1024) = jac of the CURRENT stage (i8 32x32x32, BK=128,
// counted-vmcnt pipeline). Shared memory overlaid on one raw buffer.
// ---------------------------------------------------------------------------
__global__ __launch_bounds__(256, 2) void jac_l0(
    int l0n,
    const signed char* __restrict__ w1q, const signed char* __restrict__ w0q,
    const signed char* __restrict__ w2q, const signed char* __restrict__ w3q,
    const unsigned short* __restrict__ d0m, const unsigned short* __restrict__ d1m,
    const unsigned short* __restrict__ d2m, float* __restrict__ klp,
    const float* __restrict__ yb, const float* __restrict__ kyb, Coef6 ca, int nc,
    const unsigned short* __restrict__ WtH, const unsigned short* __restrict__ WtL,
    const float* __restrict__ bias, const float* __restrict__ wrow0, float tval,
    unsigned short* __restrict__ Hhi, unsigned short* __restrict__ Hlo) {
  __shared__ __align__(16) char smraw[68672];
  const int t = threadIdx.x, l = t & 63, w = t >> 6;

  if ((int)blockIdx.x < l0n) {
    // ------------------------- L0 path (next stage) -------------------------
    unsigned short* AsH = (unsigned short*)(smraw);
    unsigned short* AsL = (unsigned short*)(smraw + 8192);
    unsigned short* BsH = (unsigned short*)(smraw + 16384);
    unsigned short* BsL = (unsigned short*)(smraw + 24576);
    const int lb = blockIdx.x;
    const int wm = w >> 1, wn = w & 1, lr = l & 15, lg = l >> 4, lr7 = lr & 7;
    const int m0 = (lb >> 4) * 32, n0 = (lb & 15) * 32;

#pragma unroll
    for (int r = 0; r < 2; ++r) {
      int g = r * 256 + t;
      int row = g >> 4;
      int gc = (g & 15) ^ (row & 7);
      size_t bo = (size_t)(n0 + row) * 128 + gc * 8;
      int db = (r * 256 + (t & 192)) * 16;
      gl_lds16(WtH + bo, (char*)BsH + db);
      gl_lds16(WtL + bo, (char*)BsL + db);
    }
    {
      int row = t >> 3, seg = t & 7;
      int gidx = (m0 + row) * 128 + seg * 16;
      float x[16];
#pragma unroll
      for (int q = 0; q < 4; ++q)
        *(float4*)&x[q * 4] = *(const float4*)&yb[gidx + q * 4];
      for (int j2 = 0; j2 < nc; ++j2) {
        float c = ca.v[j2];
#pragma unroll
        for (int q = 0; q < 4; ++q) {
          float4 u = *(const float4*)&kyb[j2 * 65536 + gidx + q * 4];
          x[q * 4 + 0] = fmaf(c, u.x, x[q * 4 + 0]);
          x[q * 4 + 1] = fmaf(c, u.y, x[q * 4 + 1]);
          x[q * 4 + 2] = fmaf(c, u.z, x[q * 4 + 2]);
          x[q * 4 + 3] = fmaf(c, u.w, x[q * 4 + 3]);
        }
      }
      u16x8 h8[2], l8[2];
#pragma unroll
      for (int e = 0; e < 16; ++e) {
        unsigned short hh = f2bf(x[e]);
        h8[e >> 3][e & 7] = hh;
        l8[e >> 3][e & 7] = f2bf(x[e] - bf2f(hh));
      }
#pragma unroll
      for (int h = 0; h < 2; ++h) {
        int gx = (seg * 2 + h) ^ (row & 7);
        *(u16x8*)((char*)AsH + row * 256 + gx * 16) = h8[h];
        *(u16x8*)((char*)AsL + row * 256 + gx * 16) = l8[h];
      }
    }
    __syncthreads();

    f32x4v acc = {0.f, 0.f, 0.f, 0.f};
#pragma unroll
    for (int ks = 0; ks < 4; ++ks) {
      int sl = ((ks * 4 + lg) ^ lr7) << 4;
      int ab = (wm * 16 + lr) * 256 + sl;
      int bb = (wn * 16 + lr) * 256 + sl;
      short8 ah = *(const short8*)((const char*)AsH + ab);
      short8 al = *(const short8*)((const char*)AsL + ab);
      short8 bh = *(const short8*)((const char*)BsH + bb);
      short8 bl = *(const short8*)((const char*)BsL + bb);
      acc = __builtin_amdgcn_mfma_f32_16x16x32_bf16(ah, bh, acc, 0, 0, 0);
      acc = __builtin_amdgcn_mfma_f32_16x16x32_bf16(ah, bl, acc, 0, 0, 0);
      acc = __builtin_amdgcn_mfma_f32_16x16x32_bf16(al, bh, acc, 0, 0, 0);
    }

    int n = n0 + wn * 16 + lr;
    float be = fmaf(tval, wrow0[n], bias[n]);
#pragma unroll
    for (int r = 0; r < 4; ++r) {
      int m = m0 + wm * 16 + lg * 4 + r;
      float v = fmaxf(acc[r] + be, 0.f);
      unsigned short h = f2bf(v);
      Hhi[m * 512 + n] = h;
      Hlo[m * 512 + n] = f2bf(v - bf2f(h));
    }
    return;
  }

  // --------------------------- jac path (current stage) ---------------------
  signed char* As = (signed char*)smraw;              // [2][16384]
  signed char* Bs = (signed char*)(smraw + 32768);    // [2][16384]
  unsigned char* Ms8 = (unsigned char*)(smraw + 65536);  // [3][2][512]
  float* red = (float*)(smraw + 68608);
  const int jx = blockIdx.x - l0n;
  const int cb = jx & 3, s0 = (jx >> 2) * 2;
  const int wm = w >> 1, wn = w & 1;
  const int lr31 = l & 31, hi = l >> 5;

  if (w < 3) {
    const unsigned short* src = (w == 0) ? d0m : (w == 1) ? d1m : d2m;
    gl_lds16(src + (size_t)s0 * 512 + l * 8, As + w * 2048);
    gl_lds16(src + (size_t)(s0 + 1) * 512 + l * 8, As + w * 2048 + 1024);
  }
  __syncthreads();
  {
    const unsigned* Mraw = (const unsigned*)As;
    unsigned* Mout = (unsigned*)Ms8;
#pragma unroll
    for (int q = 0; q < 3; ++q) {
      int i = q * 256 + t;
      unsigned lo = Mraw[2 * i], hi2 = Mraw[2 * i + 1];
      unsigned m = 0;
      if (lo & 0xFFFFu) m |= 0x000000FFu;
      if (lo >> 16)     m |= 0x0000FF00u;
      if (hi2 & 0xFFFFu) m |= 0x00FF0000u;
      if (hi2 >> 16)     m |= 0xFF000000u;
      Mout[i] = m;
    }
  }
  __syncthreads();

  auto stage = [&](int buf, const signed char* Aq, const signed char* Bq, int k0) {
#pragma unroll
    for (int i = 0; i < 8; ++i) {
      int u = i * 4 + w;
      int uu = (u < 16) ? u : (u - 16);
      int g = uu * 64 + l;
      int row = g & 127;
      int kh = (g >> 7) & 1;
      int ks = g >> 8;
      int kb = k0 + ks * 32 + kh * 16;
      if (u < 16)
        gl_lds16(Aq + (size_t)(cb * 128 + row) * 512 + kb, As + buf * 16384 + uu * 1024);
      else
        gl_lds16(Bq + (size_t)row * 512 + kb, Bs + buf * 16384 + uu * 1024);
    }
  };

  i32x16 a0[2][2], a1[2][2];
  auto phase = [&](const signed char* Aq, const signed char* Bq, int mbase) {
#pragma unroll
    for (int mt = 0; mt < 2; ++mt)
#pragma unroll
      for (int nt = 0; nt < 2; ++nt) {
        a0[mt][nt] = (i32x16)(0);
        a1[mt][nt] = (i32x16)(0);
      }
    stage(0, Aq, Bq, 0);
    int cur = 0;
    for (int k0 = 0; k0 < 512; k0 += 128) {
      if (k0 + 128 < 512) {
        stage(cur ^ 1, Aq, Bq, k0 + 128);
        asm volatile("s_waitcnt vmcnt(8)" ::: "memory");
      } else {
        asm volatile("s_waitcnt vmcnt(0)" ::: "memory");
      }
      asm volatile("s_barrier" ::: "memory");
      __builtin_amdgcn_s_setprio(1);
#pragma unroll
      for (int ks = 0; ks < 4; ++ks) {
        i32x4 af[2];
#pragma unroll
        for (int mt = 0; mt < 2; ++mt)
          af[mt] = *(const i32x4*)(As + cur * 16384 +
                                   (ks * 256 + hi * 128 + wm * 64 + mt * 32 + lr31) * 16);
        u32x4 mk0 = *(const u32x4*)&Ms8[mbase + k0 + ks * 32 + hi * 16];
        u32x4 mk1 = *(const u32x4*)&Ms8[mbase + 512 + k0 + ks * 32 + hi * 16];
#pragma unroll
        for (int nt = 0; nt < 2; ++nt) {
          u32x4 bv = *(const u32x4*)(Bs + cur * 16384 +
                                     (ks * 256 + hi * 128 + wn * 64 + nt * 32 + lr31) * 16);
          i32x4 b0 = (i32x4)(bv & mk0);
          i32x4 b1 = (i32x4)(bv & mk1);
#pragma unroll
          for (int mt = 0; mt < 2; ++mt) {
            a0[mt][nt] = __builtin_amdgcn_mfma_i32_32x32x32_i8(af[mt], b0,
                                                               a0[mt][nt], 0, 0, 0);
            a1[mt][nt] = __builtin_amdgcn_mfma_i32_32x32x32_i8(af[mt], b1,
                                                               a1[mt][nt], 0, 0, 0);
          }
        }
      }
      __builtin_amdgcn_s_setprio(0);
      asm volatile("s_waitcnt lgkmcnt(0)" ::: "memory");
      asm volatile("s_barrier" ::: "memory");
      cur ^= 1;
    }
  };

  phase(w2q, w3q, 2 * 1024);
  unsigned pg0[2][2][8], pg1[2][2][8];
#pragma unroll
  for (int mt = 0; mt < 2; ++mt)
#pragma unroll
    for (int nt = 0; nt < 2; ++nt)
#pragma unroll
      for (int p = 0; p < 8; ++p) {
        float ga = (float)a0[mt][nt][2 * p] * SCALE_G;
        float gb = (float)a0[mt][nt][2 * p + 1] * SCALE_G;
        float gc = (float)a1[mt][nt][2 * p] * SCALE_G;
        float gd = (float)a1[mt][nt][2 * p + 1] * SCALE_G;
        asm("v_cvt_pk_bf16_f32 %0, %1, %2" : "=v"(pg0[mt][nt][p]) : "v"(ga), "v"(gb));
        asm("v_cvt_pk_bf16_f32 %0, %1, %2" : "=v"(pg1[mt][nt][p]) : "v"(gc), "v"(gd));
      }

  phase(w1q, w0q, 0);

  float p0 = 0.f, p1 = 0.f;
  const unsigned char* D1b = &Ms8[1 * 1024];
#pragma unroll
  for (int mt = 0; mt < 2; ++mt) {
#pragma unroll
    for (int q = 0; q < 4; ++q) {
      int blg = cb * 128 + wm * 64 + mt * 32 + q * 8 + 4 * hi;
      uchar4 m40 = *(const uchar4*)&D1b[blg];
      uchar4 m41 = *(const uchar4*)&D1b[512 + blg];
      unsigned char mm0[4] = {m40.x, m40.y, m40.z, m40.w};
      unsigned char mm1[4] = {m41.x, m41.y, m41.z, m41.w};
#pragma unroll
      for (int e = 0; e < 4; ++e) {
        const int r = q * 4 + e;
#pragma unroll
        for (int nt = 0; nt < 2; ++nt) {
          unsigned pw0 = pg0[mt][nt][r >> 1];
          unsigned pw1 = pg1[mt][nt][r >> 1];
          unsigned short g0 = (r & 1) ? (unsigned short)(pw0 >> 16)
                                      : (unsigned short)(pw0 & 0xFFFFu);
          unsigned short g1 = (r & 1) ? (unsigned short)(pw1 >> 16)
                                      : (unsigned short)(pw1 & 0xFFFFu);
          if (mm0[e]) p0 = fmaf((float)a0[mt][nt][r], bf2f(g0), p0);
          if (mm1[e]) p1 = fmaf((float)a1[mt][nt][r], bf2f(g1), p1);
        }
      }
    }
  }
  p0 *= SCALE_J;
  p1 *= SCALE_J;
#pragma unroll
  for (int off = 1; off < 64; off <<= 1) {
    p0 += __shfl_xor(p0, off);
    p1 += __shfl_xor(p1, off);
  }
  if (l == 0) { red[w * 2] = p0; red[w * 2 + 1] = p1; }
  __syncthreads();
  if (t < 2) {
    klp[cb * 512 + s0 + t] = red[t] + red[2 + t] + red[4 + t] + red[6 + t];
  }
}

// y += sum_i db[i]*ky[i];  lp += sum_i db[i]*(sum_{4 chunks} klp[i][cb][s])
__global__ __launch_bounds__(256) void step_update(float* __restrict__ y,
                                                   float* __restrict__ lp,
                                                   const float* __restrict__ ky,
                                                   const float* __restrict__ klp_part,
                                                   Coef6 db) {
  int i = blockIdx.x * 256 + threadIdx.x;
  if (i < 65536) {
    float a = y[i];
#pragma unroll
    for (int j = 0; j < 6; ++j) a += db.v[j] * ky[j * 65536 + i];
    y[i] = a;
  }
  if (i < 512) {
    float l = lp[i];
#pragma unroll
    for (int j = 0; j < 6; ++j) {
      const float* kp = klp_part + j * 2048;
      float tr = kp[i] + kp[512 + i] + kp[1024 + i] + kp[1536 + i];
      l += db.v[j] * tr;
    }
    lp[i] = l;
  }
}

__global__ __launch_bounds__(64) void finalize(const float* __restrict__ y,
                                               const float* __restrict__ lp,
                                               float* __restrict__ out) {
  int s = blockIdx.x, l = threadIdx.x;
  float v0 = y[s * 128 + l], v1 = y[s * 128 + 64 + l];
  float sum = v0 * v0 + v1 * v1;
#pragma unroll
  for (int off = 32; off; off >>= 1) sum += __shfl_down(sum, off);
  if (l == 0) out[s] = lp[s] + (-0.5f) * (1.8378770664093453f + sum);
}

// ---------------------------------------------------------------------------
extern "C" void kernel_launch(void* const* d_in, const int* in_sizes, int n_in,
                              void* d_out, int out_size, void* d_ws, size_t ws_size,
                              hipStream_t stream) {
  const float* y_in = (const float*)d_in[0];
  const float* Ws0 = (const float*)d_in[1];
  const float* bs0 = (const float*)d_in[2];
  const float* Ws1 = (const float*)d_in[3];
  const float* bs1 = (const float*)d_in[4];
  const float* Ws2 = (const float*)d_in[5];
  const float* bs2 = (const float*)d_in[6];
  const float* Ws3 = (const float*)d_in[7];
  const float* bs3 = (const float*)d_in[8];
  float* out = (float*)d_out;

  char* ws = (char*)d_ws;
  size_t off = 0;
  auto alloc = [&](size_t bytes) {
    void* p = ws + off;
    off = (off + bytes + 255) & ~(size_t)255;
    return p;
  };
  float* y  = (float*)alloc(65536 * 4);
  float* lp = (float*)alloc(512 * 4);
  unsigned short* h0hi[2] = {(unsigned short*)alloc(262144 * 2),
                             (unsigned short*)alloc(262144 * 2)};
  unsigned short* h0lo[2] = {(unsigned short*)alloc(262144 * 2),
                             (unsigned short*)alloc(262144 * 2)};
  unsigned short* h1hi = (unsigned short*)alloc(262144 * 2);
  unsigned short* h1lo = (unsigned short*)alloc(262144 * 2);
  unsigned short* h2hi = (unsigned short*)alloc(262144 * 2);
  unsigned short* h2lo = (unsigned short*)alloc(262144 * 2);
  float* ky  = (float*)alloc(6 * 65536 * 4);
  float* klp = (float*)alloc(6 * 2048 * 4);
  unsigned short* w0tH = (unsigned short*)alloc(65536 * 2);
  unsigned short* w0tL = (unsigned short*)alloc(65536 * 2);
  unsigned short* w1tH = (unsigned short*)alloc(262144 * 2);
  unsigned short* w1tL = (unsigned short*)alloc(262144 * 2);
  unsigned short* w2tH = (unsigned short*)alloc(262144 * 2);
  unsigned short* w2tL = (unsigned short*)alloc(262144 * 2);
  unsigned short* w3tH = (unsigned short*)alloc(65536 * 2);
  unsigned short* w3tL = (unsigned short*)alloc(65536 * 2);
  signed char* w0q = (signed char*)alloc(65536);
  signed char* w1q = (signed char*)alloc(262144);
  signed char* w2q = (signed char*)alloc(262144);
  signed char* w3q = (signed char*)alloc(65536);
  (void)ws_size; (void)in_sizes; (void)n_in; (void)out_size;

  static const double DT = -0.1;
  static const double TC[6] = {0.0, 0.161, 0.327, 0.9, 0.9800255409045097, 1.0};
  static const double TA[6][5] = {
      {0, 0, 0, 0, 0},
      {0.161, 0, 0, 0, 0},
      {-0.008480655492356989, 0.335480655492357, 0, 0, 0},
      {2.8971530571054935, -6.359448489975075, 4.3622954328695815, 0, 0},
      {5.325864828439257, -11.748883564062828, 7.4955393428898365, -0.09249506636175525, 0},
      {5.86145544294642, -12.92096931784711, 8.159367898576159, -0.071584973281401,
       -0.028269050394068383}};
  static const double TB[6] = {0.09646076681806523, 0.01, 0.4798896504144996,
                               1.379008574103742, -3.290069515436081, 2.324710524099774};

  Coef6 db;
  for (int i2 = 0; i2 < 6; ++i2) db.v[i2] = (float)(DT * TB[i2]);
  Coef6 c0 = {{0, 0, 0, 0, 0, 0}};

  init_state<<<dim3(256), dim3(256), 0, stream>>>(y_in, y, lp);

  for (int blk = 0; blk < 2; ++blk) {
    const float* W0 = Ws0 + blk * 129 * 512;
    const float* b0 = bs0 + blk * 512;
    const float* W1 = Ws1 + blk * 262144;
    const float* b1 = bs1 + blk * 512;
    const float* W2 = Ws2 + blk * 262144;
    const float* b2 = bs2 + blk * 512;
    const float* W3 = Ws3 + blk * 65536;
    const float* b3 = bs3 + blk * 128;

    cast_weights<<<dim3(3840), dim3(256), 0, stream>>>(
        W0, W1, W2, W3, w0q, w0tH, w0tL, w1tH, w1tL, w1q,
        w2tH, w2tL, w3tH, w3tL, w3q, w2q);

    for (int n = 0; n < 10; ++n) {
      float tn = 1.0f + (-0.1f) * (float)n;
      for (int i = 0; i < 6; ++i) {
        const int p = i & 1;
        if (n == 0 && i == 0) {
          jac_l0<<<dim3(256), 256, 0, stream>>>(
              256, w1q, w0q, w2q, w3q, h0hi[0], h1hi, h2hi, klp,
              y, ky, c0, 0, w0tH, w0tL, b0, W0, tn, h0hi[0], h0lo[0]);
        }
        fwd_mfma<true><<<dim3(16, 16), 256, 0, stream>>>(
            h0hi[p], h0lo[p], w1tH, w1tL, b1, nullptr, h1hi, h1lo, 512, 512);
        fwd_mfma<true><<<dim3(16, 16), 256, 0, stream>>>(
            h1hi, h1lo, w2tH, w2tL, b2, nullptr, h2hi, h2lo, 512, 512);
        fwd_mfma<false><<<dim3(4, 16), 256, 0, stream>>>(
            h2hi, h2lo, w3tH, w3tL, b3, ky + i * 65536, nullptr, nullptr, 128, 512);

        if (i < 5) {
          Coef6 cn = {{0, 0, 0, 0, 0, 0}};
          for (int j = 0; j <= i; ++j) cn.v[j] = (float)(DT * TA[i + 1][j]);
          float tin = tn + (float)(TC[i + 1] * DT);
          jac_l0<<<dim3(1280), 256, 0, stream>>>(
              256, w1q, w0q, w2q, w3q, h0hi[p], h1hi, h2hi, klp + i * 2048,
              y, ky, cn, i + 1, w0tH, w0tL, b0, W0, tin, h0hi[p ^ 1], h0lo[p ^ 1]);
        } else if (n < 9) {
          float tin = tn - 0.1f;
          jac_l0<<<dim3(1280), 256, 0, stream>>>(
              256, w1q, w0q, w2q, w3q, h0hi[p], h1hi, h2hi, klp + 5 * 2048,
              y, ky, db, 6, w0tH, w0tL, b0, W0, tin, h0hi[p ^ 1], h0lo[p ^ 1]);
        } else {
          jac_l0<<<dim3(1024), 256, 0, stream>>>(
              0, w1q, w0q, w2q, w3q, h0hi[p], h1hi, h2hi, klp + 5 * 2048,
              y, ky, c0, 0, w0tH, w0tL, b0, W0, tn, h0hi[p ^ 1], h0lo[p ^ 1]);
        }
      }
      step_update<<<dim3(256), dim3(256), 0, stream>>>(y, lp, ky, klp, db);
    }
  }
  finalize<<<dim3(512), dim3(64), 0, stream>>>(y, lp, out);
}